// Round 9
// baseline (261.907 us; speedup 1.0000x reference)
//
#include <hip/hip_runtime.h>
#include <math.h>

// Problem constants
constexpr int Bb = 2, Ss = 2048, Dd = 1024, Hh = 16, Kk = 16;
constexpr float DELTA = 0.02f;   // candidate margin (~30 sigma of bf16 approx error)

typedef __bf16 bf16x8 __attribute__((ext_vector_type(8)));
typedef __bf16 bf16x4 __attribute__((ext_vector_type(4)));
typedef float  f32x4  __attribute__((ext_vector_type(4)));

__device__ __forceinline__ void gld_lds16(const void* g, void* l) {
    __builtin_amdgcn_global_load_lds(
        (const __attribute__((address_space(1))) unsigned int*)g,
        (__attribute__((address_space(3))) unsigned int*)l, 16, 0, 0);
}

// ---------------------------------------------------------------------------
// Merged prep: bid<1024 -> float4 inits (Y=0, hbuf=0, qkvsel=0, imp=0,
// zbuf=bv); 1024..5119 -> per-batch transpose x -> xbT AND pack x -> xb
// from the same tile (x read ONCE); bid>=5120 -> Ws1 T -> W1Th.
// ---------------------------------------------------------------------------
__global__ void __launch_bounds__(256) prep_kernel(
    const float* __restrict__ x, __bf16* __restrict__ xb,
    __bf16* __restrict__ xbT,
    float* __restrict__ imp, float* __restrict__ hbuf,
    float* __restrict__ qkvsel, int* __restrict__ ccount,
    const float* __restrict__ Ws1, __bf16* __restrict__ W1Th,
    const float* __restrict__ bv,
    float* __restrict__ Y, float* __restrict__ zbuf)
{
    __shared__ float tile[32][33];
    const int bid = blockIdx.x;
    const int t   = threadIdx.x;

    if (bid < 1024) {
        int i = bid * 256 + t;                       // float4 index
        float4 z4 = {0.f, 0.f, 0.f, 0.f};
        if (i < 131072) ((float4*)Y)[i] = z4;
        if (i < 16384)  ((float4*)hbuf)[i] = z4;
        if (i < 24576)  ((float4*)qkvsel)[i] = z4;
        if (i < 8192)   ((float4*)zbuf)[i] = ((const float4*)bv)[i & 255];
        if (i < 1024)   ((float4*)imp)[i] = z4;
        if (i < Bb)     ccount[i] = 0;
        return;
    }
    if (bid < 5120) {
        // transpose + pack: xbT[b][c][r] = x[b][r][c]; xb = bf16(x)
        int tid = bid - 1024;          // 0..4095, 2048 tiles per b
        int b   = tid >> 11;
        int rem = tid & 2047;
        int rt  = rem >> 5;            // 64 row-tiles (2048/32)
        int ct  = rem & 31;            // 32 col-tiles (1024/32)
        int tx = t & 31, ty = t >> 5;
        const float* xp = x + (size_t)b * Ss * Dd;
        __bf16* xbp = xb + (size_t)b * Ss * Dd;
        #pragma unroll
        for (int i2 = 0; i2 < 32; i2 += 8) {
            float v = xp[(size_t)(rt * 32 + ty + i2) * 1024 + ct * 32 + tx];
            tile[ty + i2][tx] = v;
            xbp[(size_t)(rt * 32 + ty + i2) * 1024 + ct * 32 + tx] = (__bf16)v;
        }
        __syncthreads();
        __bf16* xT = xbT + (size_t)b * Dd * Ss;
        #pragma unroll
        for (int i2 = 0; i2 < 32; i2 += 8)
            xT[(size_t)(ct * 32 + ty + i2) * 2048 + rt * 32 + tx] = (__bf16)tile[tx][ty + i2];
        return;
    }
    {
        int tid = bid - 5120;          // 0..511
        int n0 = (tid & 15) * 32;
        int k0 = (tid >> 4) * 32;
        int tx = t & 31, ty = t >> 5;
        #pragma unroll
        for (int i2 = 0; i2 < 32; i2 += 8)
            tile[ty + i2][tx] = Ws1[(size_t)(k0 + ty + i2) * 512 + n0 + tx];
        __syncthreads();
        #pragma unroll
        for (int i2 = 0; i2 < 32; i2 += 8)
            W1Th[(size_t)(n0 + ty + i2) * 1024 + k0 + tx] = (__bf16)tile[tx][ty + i2];
    }
}

// ---------------------------------------------------------------------------
// Indexer GEMM: imp = rowsum(relu(x@Ws1+bs1)*Ws2). 64x128 tile, BK=64,
// 4 waves, XOR-swizzled LDS. Grid (4 cb, 64 mtiles) = 256 blocks. NO fence.
// ---------------------------------------------------------------------------
__global__ void __launch_bounds__(256) gemm_ind(
    const __bf16* __restrict__ xb, const __bf16* __restrict__ W1Th,
    const float* __restrict__ bs1, const float* __restrict__ Ws2,
    float* __restrict__ imp)
{
    __shared__ __bf16 As[64 * 64];
    __shared__ __bf16 Bs[128 * 64];

    const int cb   = blockIdx.x;
    const int bm   = blockIdx.y * 64;
    const int t    = threadIdx.x;
    const int wave = t >> 6;
    const int lane = t & 63;
    const int wm   = (wave & 1) * 32;
    const int wn   = (wave >> 1) * 64;
    const int fr   = lane & 15;
    const int fq   = lane >> 4;
    const int K    = Dd;

    const __bf16* BT = W1Th + (size_t)cb * 128 * 1024;

    f32x4 acc[2][4] = {};

    for (int k0 = 0; k0 < K; k0 += 64) {
        #pragma unroll
        for (int l = 0; l < 2; ++l) {
            int c = l * 256 + t;
            int row = c >> 3, seg = (c & 7) ^ (row & 7);
            gld_lds16(xb + (size_t)(bm + row) * K + k0 + seg * 8,
                      As + (size_t)(l * 256 + wave * 64) * 8);
        }
        #pragma unroll
        for (int l = 0; l < 4; ++l) {
            int c = l * 256 + t;
            int row = c >> 3, seg = (c & 7) ^ (row & 7);
            gld_lds16(BT + (size_t)row * K + k0 + seg * 8,
                      Bs + (size_t)(l * 256 + wave * 64) * 8);
        }
        __syncthreads();
        #pragma unroll
        for (int s = 0; s < 2; ++s) {
            bf16x8 af[2], bf[4];
            #pragma unroll
            for (int i = 0; i < 2; ++i) {
                int row = wm + i * 16 + fr;
                af[i] = *(const bf16x8*)(As + row * 64 + (((s * 4 + fq) ^ (row & 7)) * 8));
            }
            #pragma unroll
            for (int j = 0; j < 4; ++j) {
                int row = wn + j * 16 + fr;
                bf[j] = *(const bf16x8*)(Bs + row * 64 + (((s * 4 + fq) ^ (row & 7)) * 8));
            }
            #pragma unroll
            for (int i = 0; i < 2; ++i)
                #pragma unroll
                for (int j = 0; j < 4; ++j)
                    acc[i][j] = __builtin_amdgcn_mfma_f32_16x16x32_bf16(af[i], bf[j], acc[i][j], 0, 0, 0);
        }
        __syncthreads();
    }

    const int cr = (lane >> 4) * 4;
    const int cc = lane & 15;
    float bb[4], w2[4];
    #pragma unroll
    for (int j = 0; j < 4; ++j) {
        int col = cb * 128 + wn + j * 16 + cc;
        bb[j] = bs1[col];
        w2[j] = Ws2[col];
    }
    #pragma unroll
    for (int i = 0; i < 2; ++i) {
        #pragma unroll
        for (int r = 0; r < 4; ++r) {
            float vsum = 0.f;
            #pragma unroll
            for (int j = 0; j < 4; ++j)
                vsum += fmaxf(acc[i][j][r] + bb[j], 0.f) * w2[j];
            #pragma unroll
            for (int off = 8; off > 0; off >>= 1)
                vsum += __shfl_xor(vsum, off, 16);
            if (cc == 0)
                atomicAdd(imp + (bm + wm + i * 16 + cr + r), vsum);
        }
    }
}

// ---------------------------------------------------------------------------
// FAST candidate generation (proven R8): wave-0 argmax over LDS with no
// syncthreads in the 16-iter loop; threshold band with 256 threads.
// ---------------------------------------------------------------------------
__global__ void __launch_bounds__(256) topk_fast(
    const float* __restrict__ imp, int* __restrict__ cand_idx,
    int* __restrict__ ccount)
{
    __shared__ float vals[2048];
    __shared__ float thr_s;
    __shared__ int   cnt_s;
    const int b = blockIdx.x;
    const int t = threadIdx.x;

    #pragma unroll
    for (int e = 0; e < 8; ++e)
        vals[t + 256 * e] = imp[b * Ss + t + 256 * e];
    __syncthreads();

    if (t < 64) {
        const int base = t * 32;
        for (int it = 0; it < Kk; ++it) {
            float best = -1e30f; int bidx = 0x7fffffff;
            #pragma unroll 8
            for (int j = 0; j < 32; ++j) {
                float v = vals[base + j];
                if (v > best) { best = v; bidx = base + j; }
            }
            #pragma unroll
            for (int off = 32; off > 0; off >>= 1) {
                float ov = __shfl_xor(best, off, 64);
                int   oi = __shfl_xor(bidx, off, 64);
                if (ov > best || (ov == best && oi < bidx)) { best = ov; bidx = oi; }
            }
            if (t == 0) {
                cand_idx[b * 64 + it] = bidx;
                vals[bidx] = -1e30f;
                if (it == Kk - 1) { thr_s = best - DELTA; cnt_s = Kk; }
            }
        }
    }
    __syncthreads();

    float thr = thr_s;
    #pragma unroll
    for (int e = 0; e < 8; ++e) {
        if (vals[t + 256 * e] > thr) {
            int p = atomicAdd(&cnt_s, 1);
            if (p < 64) cand_idx[b * 64 + p] = t + 256 * e;
        }
    }
    __syncthreads();
    if (t == 0) ccount[b] = min(cnt_s, 64);
}

// ---------------------------------------------------------------------------
// Exact f32 rescore, phase 1 (unchanged, proven). NO trailing fence.
// ---------------------------------------------------------------------------
__global__ void __launch_bounds__(256) rescore_h(
    const float* __restrict__ x, const float* __restrict__ Ws1,
    const int* __restrict__ cand_idx, const int* __restrict__ ccount,
    float* __restrict__ hbuf)
{
    const int c = blockIdx.x, kc = blockIdx.y, b = blockIdx.z;
    if (c >= ccount[b]) return;
    const int row = cand_idx[b * 64 + c];
    const int t = threadIdx.x;
    const int k0 = kc * 64;

    __shared__ float xs[64];
    if (t < 16)
        ((float4*)xs)[t] = ((const float4*)(x + ((size_t)(b * Ss + row)) * Dd + k0))[t];
    __syncthreads();

    float a0 = 0.f, a1 = 0.f;
    const float* W = Ws1 + (size_t)k0 * 512;
    #pragma unroll 16
    for (int kk = 0; kk < 64; ++kk) {
        float xv = xs[kk];
        a0 = fmaf(xv, W[kk * 512 + t], a0);
        a1 = fmaf(xv, W[kk * 512 + t + 256], a1);
    }
    float* hb = hbuf + ((size_t)(b * 64 + c)) * 512;
    atomicAdd(hb + t, a0);
    atomicAdd(hb + t + 256, a1);
}

// ---------------------------------------------------------------------------
// MERGED rescore phase-2 + final selection (unchanged, proven R6/R8).
// ---------------------------------------------------------------------------
__global__ void __launch_bounds__(256) rescore_fin_sel(
    const float* __restrict__ hbuf, const float* __restrict__ bs1,
    const float* __restrict__ Ws2, const int* __restrict__ cand_idx,
    const int* __restrict__ ccount, int* __restrict__ sel_idx)
{
    const int b = blockIdx.x;
    const int t = threadIdx.x;
    __shared__ float czv[64];
    __shared__ int   cidx[64];
    const int cntb = ccount[b];

    {
        const int cc = t >> 2, part = t & 3;
        const float* hb = hbuf + ((size_t)(b * 64 + cc)) * 512;
        float z = 0.f;
        const int j0 = part * 128;
        for (int j = j0; j < j0 + 128; ++j)
            z += fmaxf(hb[j] + bs1[j], 0.f) * Ws2[j];
        z += __shfl_xor(z, 1, 4);
        z += __shfl_xor(z, 2, 4);
        if (part == 0) { czv[cc] = z; cidx[cc] = cand_idx[b * 64 + cc]; }
    }
    __syncthreads();

    if (t < 64) {
        float val = (t < cntb) ? czv[t] : -1e30f;
        int   row = (t < cntb) ? cidx[t] : 0x7fffffff;
        for (int it = 0; it < Kk; ++it) {
            float bv = val; int br = row;
            #pragma unroll
            for (int off = 1; off < 64; off <<= 1) {
                float ov = __shfl_xor(bv, off, 64);
                int   orw = __shfl_xor(br, off, 64);
                if (ov > bv || (ov == bv && orw < br)) { bv = ov; br = orw; }
            }
            if (row == br) val = -1e30f;
            if (t == 0) sel_idx[b * Kk + it] = br;
        }
    }
}

// ---------------------------------------------------------------------------
// Exact f32 projections of the 32 selected rows (unchanged, proven).
// Grid (8 coltiles, 3 mats, 8 kchunks).
// ---------------------------------------------------------------------------
__global__ void __launch_bounds__(256) proj_sel(
    const float* __restrict__ x,
    const float* __restrict__ Wq, const float* __restrict__ Wk,
    const float* __restrict__ Wv,
    const int* __restrict__ sel_idx, float* __restrict__ qkvsel)
{
    const int cx = blockIdx.x;
    const int m  = blockIdx.y;
    const int kc = blockIdx.z;
    const int t  = threadIdx.x;
    __shared__ int   sj[32];
    __shared__ float xs[32][128];

    if (t < 32) sj[t] = sel_idx[t];
    __syncthreads();

    const int k0 = kc * 128;
    #pragma unroll
    for (int l = 0; l < 4; ++l) {
        int c = l * 256 + t;
        int r = c >> 5, kq = c & 31;
        int b = r >> 4;
        float4 v = *(const float4*)(x + ((size_t)(b * Ss + sj[r])) * Dd + k0 + kq * 4);
        *(float4*)&xs[r][kq * 4] = v;
    }
    __syncthreads();

    const float* W = (m == 0) ? Wq : (m == 1) ? Wk : Wv;
    const int col = cx * 128 + (t & 127);
    const int rh  = t >> 7;
    float acc[16] = {};
    #pragma unroll 4
    for (int kk = 0; kk < 128; ++kk) {
        float wv = W[(size_t)(k0 + kk) * 1024 + col];
        #pragma unroll
        for (int r = 0; r < 16; ++r)
            acc[r] = fmaf(xs[rh * 16 + r][kk], wv, acc[r]);
    }
    #pragma unroll
    for (int r = 0; r < 16; ++r)
        atomicAdd(qkvsel + (size_t)(m * 32 + rh * 16 + r) * 1024 + col, acc[r]);
}

// ---------------------------------------------------------------------------
// Build the algebraic operands (unchanged, proven). Grid (8,16,2).
// ---------------------------------------------------------------------------
__global__ void __launch_bounds__(256) build_cdvo(
    const float* __restrict__ Wq, const float* __restrict__ Wk,
    const float* __restrict__ Wo,
    const float* __restrict__ bq, const float* __restrict__ bk,
    const float* __restrict__ bv,
    const float* __restrict__ qkvsel, float* __restrict__ beta,
    __bf16* __restrict__ ET, __bf16* __restrict__ VoT)
{
    const int nx = blockIdx.x;
    const int h  = blockIdx.y;
    const int b  = blockIdx.z;
    const int t  = threadIdx.x;
    __shared__ float qs[16][64], ks[16][64], vs[16][64];
    __shared__ float wt[128][65];

    #pragma unroll
    for (int l = 0; l < 12; ++l) {
        int c = l * 256 + t;
        int mat = c >> 10, rem = c & 1023;
        int row = rem >> 6, d = rem & 63;
        const float* bias = (mat == 0) ? bq : (mat == 1) ? bk : bv;
        float v = qkvsel[(size_t)(mat * 32 + b * 16 + row) * 1024 + h * 64 + d]
                + bias[h * 64 + d];
        if (mat == 0) qs[row][d] = v;
        else if (mat == 1) ks[row][d] = v;
        else vs[row][d] = v;
    }
    __syncthreads();

    if (nx == 0 && t < 16) {
        float a = 0.f;
        #pragma unroll 8
        for (int d = 0; d < 64; ++d) a = fmaf(bq[h * 64 + d], ks[t][d], a);
        beta[b * 256 + h * 16 + t] = a;
    }

    const int nl = t & 127;
    const int n  = nx * 128 + nl;
    const int sg = t >> 7;

    // ---- C (Wq tile x ks) ----
    #pragma unroll
    for (int l = 0; l < 8; ++l) {
        int c = l * 256 + t;
        int rn = c >> 4, c4 = c & 15;
        float4 v = *(const float4*)(Wq + (size_t)(nx * 128 + rn) * 1024 + h * 64 + c4 * 4);
        wt[rn][c4 * 4 + 0] = v.x; wt[rn][c4 * 4 + 1] = v.y;
        wt[rn][c4 * 4 + 2] = v.z; wt[rn][c4 * 4 + 3] = v.w;
    }
    __syncthreads();
    {
        float acc[8] = {};
        #pragma unroll 8
        for (int d = 0; d < 64; ++d) {
            float wv = wt[nl][d];
            #pragma unroll
            for (int s = 0; s < 8; ++s)
                acc[s] = fmaf(wv, ks[sg * 8 + s][d], acc[s]);
        }
        #pragma unroll
        for (int s = 0; s < 8; ++s)
            ET[(size_t)(b * 512 + h * 16 + sg * 8 + s) * 1024 + n] = (__bf16)acc[s];
    }
    __syncthreads();

    // ---- D (Wk tile x qs) ----
    #pragma unroll
    for (int l = 0; l < 8; ++l) {
        int c = l * 256 + t;
        int rn = c >> 4, c4 = c & 15;
        float4 v = *(const float4*)(Wk + (size_t)(nx * 128 + rn) * 1024 + h * 64 + c4 * 4);
        wt[rn][c4 * 4 + 0] = v.x; wt[rn][c4 * 4 + 1] = v.y;
        wt[rn][c4 * 4 + 2] = v.z; wt[rn][c4 * 4 + 3] = v.w;
    }
    __syncthreads();
    {
        float acc[8] = {};
        #pragma unroll 8
        for (int d = 0; d < 64; ++d) {
            float wv = wt[nl][d];
            #pragma unroll
            for (int s = 0; s < 8; ++s)
                acc[s] = fmaf(wv, qs[sg * 8 + s][d], acc[s]);
        }
        #pragma unroll
        for (int s = 0; s < 8; ++s)
            ET[(size_t)(b * 512 + 256 + h * 16 + sg * 8 + s) * 1024 + n] = (__bf16)acc[s];
    }

    // ---- Vo^T (Wo direct x vs) ----
    {
        float acc[8] = {};
        #pragma unroll 8
        for (int d = 0; d < 64; ++d) {
            float wv = Wo[(size_t)(h * 64 + d) * 1024 + n];
            #pragma unroll
            for (int s = 0; s < 8; ++s)
                acc[s] = fmaf(wv, vs[sg * 8 + s][d], acc[s]);
        }
        #pragma unroll
        for (int s = 0; s < 8; ++s)
            VoT[((size_t)b * 1024 + n) * 256 + h * 16 + sg * 8 + s] = (__bf16)acc[s];
    }
}

// ---------------------------------------------------------------------------
// Score GEMM with FUSED sparse softmax epilogue. S = X @ E (E = [C|D]).
// Blocks with bn<256: each 16-lane group holds one head's 16 selected-key
// scores for a row -> softmax((s+beta)*0.125) via 4 shfl_xor(16), write
// Wsp bf16 directly (Ssp buffer eliminated). Blocks bn>=256: write SdT
// transposed for the dense column softmax. Grid (4,32,2) = 256 blocks.
// ---------------------------------------------------------------------------
__global__ void __launch_bounds__(256) gemm_scores(
    const __bf16* __restrict__ xb, const __bf16* __restrict__ ET,
    const float* __restrict__ beta, __bf16* __restrict__ Wsp,
    float* __restrict__ SdT)
{
    __shared__ __bf16 As[64 * 64];
    __shared__ __bf16 Bs[128 * 64];

    const int b    = blockIdx.z;
    const int bn   = blockIdx.x * 128;
    const int bm   = blockIdx.y * 64;
    const int t    = threadIdx.x;
    const int wave = t >> 6;
    const int lane = t & 63;
    const int wm   = (wave & 1) * 32;
    const int wn   = (wave >> 1) * 64;
    const int fr   = lane & 15;
    const int fq   = lane >> 4;
    const int K    = Dd;

    const __bf16* A  = xb + (size_t)b * Ss * Dd;
    const __bf16* BT = ET + (size_t)b * 512 * 1024 + (size_t)bn * 1024;

    f32x4 acc[2][4] = {};

    for (int k0 = 0; k0 < K; k0 += 64) {
        #pragma unroll
        for (int l = 0; l < 2; ++l) {
            int c = l * 256 + t;
            int row = c >> 3, seg = (c & 7) ^ (row & 7);
            gld_lds16(A + (size_t)(bm + row) * K + k0 + seg * 8,
                      As + (size_t)(l * 256 + wave * 64) * 8);
        }
        #pragma unroll
        for (int l = 0; l < 4; ++l) {
            int c = l * 256 + t;
            int row = c >> 3, seg = (c & 7) ^ (row & 7);
            gld_lds16(BT + (size_t)row * K + k0 + seg * 8,
                      Bs + (size_t)(l * 256 + wave * 64) * 8);
        }
        __syncthreads();
        #pragma unroll
        for (int s = 0; s < 2; ++s) {
            bf16x8 af[2], bf[4];
            #pragma unroll
            for (int i = 0; i < 2; ++i) {
                int row = wm + i * 16 + fr;
                af[i] = *(const bf16x8*)(As + row * 64 + (((s * 4 + fq) ^ (row & 7)) * 8));
            }
            #pragma unroll
            for (int j = 0; j < 4; ++j) {
                int row = wn + j * 16 + fr;
                bf[j] = *(const bf16x8*)(Bs + row * 64 + (((s * 4 + fq) ^ (row & 7)) * 8));
            }
            #pragma unroll
            for (int i = 0; i < 2; ++i)
                #pragma unroll
                for (int j = 0; j < 4; ++j)
                    acc[i][j] = __builtin_amdgcn_mfma_f32_16x16x32_bf16(af[i], bf[j], acc[i][j], 0, 0, 0);
        }
        __syncthreads();
    }

    const int cr = (lane >> 4) * 4;
    const int cc = lane & 15;
    if (bn < 256) {
        // fused sparse softmax: 16 lanes (cc) = 16 selected keys of one head
        #pragma unroll
        for (int j = 0; j < 4; ++j) {
            int col = bn + wn + j * 16 + cc;
            float bt = beta[b * 256 + col];
            #pragma unroll
            for (int i = 0; i < 2; ++i) {
                #pragma unroll
                for (int r = 0; r < 4; ++r) {
                    float e = __expf((acc[i][j][r] + bt) * 0.125f);
                    float ps = e;
                    ps += __shfl_xor(ps, 1, 16);
                    ps += __shfl_xor(ps, 2, 16);
                    ps += __shfl_xor(ps, 4, 16);
                    ps += __shfl_xor(ps, 8, 16);
                    int row = bm + wm + i * 16 + cr + r;
                    Wsp[((size_t)b * 2048 + row) * 256 + col] = (__bf16)(e / ps);
                }
            }
        }
    } else {
        #pragma unroll
        for (int j = 0; j < 4; ++j) {
            int col = bn + wn + j * 16 + cc;
            #pragma unroll
            for (int i = 0; i < 2; ++i) {
                int row0 = bm + wm + i * 16 + cr;
                *(f32x4*)(SdT + ((size_t)b * 256 + col - 256) * 2048 + row0) = acc[i][j];
            }
        }
    }
}

// ---------------------------------------------------------------------------
// Dense softmax only (sparse half fused into gemm_scores). Per (t,h)
// column over all 2048 keys. Grid (256, 2).
// ---------------------------------------------------------------------------
__global__ void __launch_bounds__(256) sm_dense(
    const float* __restrict__ SdT, __bf16* __restrict__ WdT)
{
    const int b = blockIdx.y, cx = blockIdx.x;
    const int t = threadIdx.x;
    __shared__ float red[256];
    const float* Sp = SdT + ((size_t)b * 256 + cx) * 2048;
    float4 v0 = *(const float4*)(Sp + t * 8);
    float4 v1 = *(const float4*)(Sp + t * 8 + 4);
    float e[8];
    e[0] = __expf(v0.x * 0.125f); e[1] = __expf(v0.y * 0.125f);
    e[2] = __expf(v0.z * 0.125f); e[3] = __expf(v0.w * 0.125f);
    e[4] = __expf(v1.x * 0.125f); e[5] = __expf(v1.y * 0.125f);
    e[6] = __expf(v1.z * 0.125f); e[7] = __expf(v1.w * 0.125f);
    float ps = 0.f;
    #pragma unroll
    for (int i = 0; i < 8; ++i) ps += e[i];
    red[t] = ps;
    __syncthreads();
    for (int off = 128; off > 0; off >>= 1) {
        if (t < off) red[t] += red[t + off];
        __syncthreads();
    }
    float inv = 1.f / red[0];
    bf16x8 w;
    #pragma unroll
    for (int i = 0; i < 8; ++i) w[i] = (__bf16)(e[i] * inv);
    *(bf16x8*)(WdT + ((size_t)b * 256 + cx) * 2048 + t * 8) = w;
}

// ---------------------------------------------------------------------------
// Shared GEMM tile body (64x128, BK=64, 4 waves, XOR-swizzled LDS).
// sel16 != nullptr: rows matching sel16[0..15] store bias only (their
// true value is accumulated later directly into out by dense_out2).
// ---------------------------------------------------------------------------
__device__ __forceinline__ void gemm_bt_body(
    __bf16* As, __bf16* Bs,
    const __bf16* __restrict__ A, const __bf16* __restrict__ BT,
    const float* __restrict__ bias, float* __restrict__ C,
    int N, int K, int bm, int bn, int kc, int kchunks, int t,
    const int* sel16)
{
    const int wave = t >> 6;
    const int lane = t & 63;
    const int wm   = (wave & 1) * 32;
    const int wn   = (wave >> 1) * 64;
    const int fr   = lane & 15;
    const int fq   = lane >> 4;
    const int KC   = K / kchunks;
    const int kend = (kc + 1) * KC;

    f32x4 acc[2][4] = {};

    for (int k0 = kc * KC; k0 < kend; k0 += 64) {
        #pragma unroll
        for (int l = 0; l < 2; ++l) {
            int c = l * 256 + t;
            int row = c >> 3, seg = (c & 7) ^ (row & 7);
            gld_lds16(A + (size_t)(bm + row) * K + k0 + seg * 8,
                      As + (size_t)(l * 256 + wave * 64) * 8);
        }
        #pragma unroll
        for (int l = 0; l < 4; ++l) {
            int c = l * 256 + t;
            int row = c >> 3, seg = (c & 7) ^ (row & 7);
            gld_lds16(BT + (size_t)(bn + row) * K + k0 + seg * 8,
                      Bs + (size_t)(l * 256 + wave * 64) * 8);
        }
        __syncthreads();
        #pragma unroll
        for (int s = 0; s < 2; ++s) {
            bf16x8 af[2], bf[4];
            #pragma unroll
            for (int i = 0; i < 2; ++i) {
                int row = wm + i * 16 + fr;
                af[i] = *(const bf16x8*)(As + row * 64 + (((s * 4 + fq) ^ (row & 7)) * 8));
            }
            #pragma unroll
            for (int j = 0; j < 4; ++j) {
                int row = wn + j * 16 + fr;
                bf[j] = *(const bf16x8*)(Bs + row * 64 + (((s * 4 + fq) ^ (row & 7)) * 8));
            }
            #pragma unroll
            for (int i = 0; i < 2; ++i)
                #pragma unroll
                for (int j = 0; j < 4; ++j)
                    acc[i][j] = __builtin_amdgcn_mfma_f32_16x16x32_bf16(af[i], bf[j], acc[i][j], 0, 0, 0);
        }
        __syncthreads();
    }

    const int cr = (lane >> 4) * 4;
    const int cc = lane & 15;
    #pragma unroll
    for (int j = 0; j < 4; ++j) {
        int col = bn + wn + j * 16 + cc;
        if (kchunks == 1) {
            float bb = bias ? bias[col] : 0.f;
            #pragma unroll
            for (int i = 0; i < 2; ++i) {
                #pragma unroll
                for (int r = 0; r < 4; ++r) {
                    int row = bm + wm + i * 16 + cr + r;
                    float v = acc[i][j][r] + bb;
                    if (sel16) {
                        bool issel = false;
                        #pragma unroll
                        for (int s2 = 0; s2 < 16; ++s2) issel |= (row == sel16[s2]);
                        if (issel) v = bb;
                    }
                    C[(size_t)row * N + col] = v;
                }
            }
        } else {
            #pragma unroll
            for (int i = 0; i < 2; ++i)
                #pragma unroll
                for (int r = 0; r < 4; ++r)
                    atomicAdd(C + (size_t)(bm + wm + i * 16 + cr + r) * N + col, acc[i][j][r]);
        }
    }
}

// ---------------------------------------------------------------------------
// FUSED output GEMMs: id<512 -> out = W_sp @ Vo + bo (selected rows get
// bias-only; dense_out2 accumulates their true values later); id>=512 ->
// Y = W_dn @ X (split-K x2, atomics). Grid 640.
// ---------------------------------------------------------------------------
__global__ void __launch_bounds__(256) gemm_bt2x(
    const __bf16* __restrict__ Wsp, const __bf16* __restrict__ VoT,
    const float* __restrict__ bo, float* __restrict__ out,
    const __bf16* __restrict__ WdT, const __bf16* __restrict__ xbT,
    float* __restrict__ Y, const int* __restrict__ sel_idx)
{
    __shared__ __bf16 As[64 * 64];
    __shared__ __bf16 Bs[128 * 64];
    __shared__ int sjs[16];
    const int t = threadIdx.x;
    int id = blockIdx.x;
    if (id < 512) {
        int bx = id & 7, by = (id >> 3) & 31, bz = id >> 8;
        if (t < 16) sjs[t] = sel_idx[bz * 16 + t];
        // body's internal __syncthreads() (first k-iter) orders sjs for the epilogue
        gemm_bt_body(As, Bs,
                     Wsp + (size_t)bz * 2048 * 256, VoT + (size_t)bz * 1024 * 256,
                     bo, out + (size_t)bz * 2048 * 1024,
                     1024, 256, by * 64, bx * 128, 0, 1, t, sjs);
    } else {
        id -= 512;
        int bx = id & 7, by = (id >> 3) & 3, z = id >> 5;   // z in 0..3
        int batch = z >> 1, kc = z & 1;
        gemm_bt_body(As, Bs,
                     WdT + (size_t)batch * 256 * 2048, xbT + (size_t)batch * 1024 * 2048,
                     nullptr, Y + (size_t)batch * 256 * 1024,
                     1024, 2048, by * 64, bx * 128, kc, 2, t, nullptr);
    }
}

// ---------------------------------------------------------------------------
// Dense finalize A (split-K, 256 blocks): zbuf (init bv) += Y @ Wv chunk.
// Grid (16 h, 8 kc, 2 b).
// ---------------------------------------------------------------------------
__global__ void __launch_bounds__(256) dense_z2(
    const float* __restrict__ Y, const float* __restrict__ Wv,
    float* __restrict__ zbuf)
{
    const int h = blockIdx.x, kc = blockIdx.y, b = blockIdx.z;
    const int t = threadIdx.x;
    __shared__ float Ys[16][128];
    const int k0 = kc * 128;
    #pragma unroll
    for (int l = 0; l < 2; ++l) {
        int c = l * 256 + t;
        int row = c >> 5, c4 = c & 31;
        *(float4*)&Ys[row][c4 * 4] =
            *(const float4*)(Y + ((size_t)(b * 256 + h * 16 + row)) * 1024 + k0 + c4 * 4);
    }
    __syncthreads();
    const int d = t & 63, tg = t >> 6;
    float acc[4] = {};
    #pragma unroll 8
    for (int kk = 0; kk < 128; ++kk) {
        float wv = Wv[(size_t)(k0 + kk) * 1024 + h * 64 + d];
        #pragma unroll
        for (int tt = 0; tt < 4; ++tt)
            acc[tt] = fmaf(Ys[tg * 4 + tt][kk], wv, acc[tt]);
    }
    #pragma unroll
    for (int tt = 0; tt < 4; ++tt)
        atomicAdd(zbuf + ((size_t)(b * 16 + tg * 4 + tt)) * 1024 + h * 64 + d, acc[tt]);
}

// ---------------------------------------------------------------------------
// Dense finalize B (split-K, 256 blocks): out[sel rows] (pre-init bo by
// gemm_bt2x) += z @ Wo chunk, accumulated DIRECTLY into out (obuf and
// scatter eliminated). Grid (16 ntiles of 64, 8 kc, 2 b).
// ---------------------------------------------------------------------------
__global__ void __launch_bounds__(256) dense_out2(
    const float* __restrict__ zbuf, const float* __restrict__ Wo,
    const int* __restrict__ sel_idx, float* __restrict__ out)
{
    const int nt = blockIdx.x, kc = blockIdx.y, b = blockIdx.z;
    const int t = threadIdx.x;
    __shared__ float zs[16][128];
    __shared__ int sj[16];
    if (t < 16) sj[t] = sel_idx[b * 16 + t];
    const int k0 = kc * 128;
    #pragma unroll
    for (int l = 0; l < 2; ++l) {
        int c = l * 256 + t;
        int row = c >> 5, c4 = c & 31;
        *(float4*)&zs[row][c4 * 4] =
            *(const float4*)(zbuf + ((size_t)(b * 16 + row)) * 1024 + k0 + c4 * 4);
    }
    __syncthreads();
    const int n = nt * 64 + (t & 63), tg = t >> 6;
    float acc[4] = {};
    #pragma unroll 8
    for (int kk = 0; kk < 128; ++kk) {
        float wv = Wo[(size_t)(k0 + kk) * 1024 + n];
        #pragma unroll
        for (int tt = 0; tt < 4; ++tt)
            acc[tt] = fmaf(zs[tg * 4 + tt][kk], wv, acc[tt]);
    }
    #pragma unroll
    for (int tt = 0; tt < 4; ++tt)
        atomicAdd(out + ((size_t)(b * 2048 + sj[tg * 4 + tt])) * 1024 + n, acc[tt]);
}

// ---------------------------------------------------------------------------
extern "C" void kernel_launch(void* const* d_in, const int* in_sizes, int n_in,
                              void* d_out, int out_size, void* d_ws, size_t ws_size,
                              hipStream_t stream)
{
    const float* x   = (const float*)d_in[0];
    const float* Wq  = (const float*)d_in[1];
    const float* bq  = (const float*)d_in[2];
    const float* Wk  = (const float*)d_in[3];
    const float* bk  = (const float*)d_in[4];
    const float* Wv  = (const float*)d_in[5];
    const float* bv  = (const float*)d_in[6];
    const float* Wo  = (const float*)d_in[7];
    const float* bo  = (const float*)d_in[8];
    const float* Ws1 = (const float*)d_in[9];
    const float* bs1 = (const float*)d_in[10];
    const float* Ws2 = (const float*)d_in[11];
    float* out = (float*)d_out;

    const size_t MSD = (size_t)Bb * Ss * Dd;   // 4,194,304

    char* p = (char*)d_ws;
    __bf16* xb    = (__bf16*)p; p += MSD * sizeof(__bf16);
    __bf16* xbT   = (__bf16*)p; p += MSD * sizeof(__bf16);
    __bf16* W1Th  = (__bf16*)p; p += (size_t)512 * 1024 * sizeof(__bf16);
    __bf16* ET    = (__bf16*)p; p += (size_t)2 * 512 * 1024 * sizeof(__bf16);
    __bf16* VoT   = (__bf16*)p; p += (size_t)2 * 1024 * 256 * sizeof(__bf16);
    __bf16* Wsp   = (__bf16*)p; p += (size_t)2 * 2048 * 256 * sizeof(__bf16);
    __bf16* WdT   = (__bf16*)p; p += (size_t)2 * 256 * 2048 * sizeof(__bf16);
    float* SdT    = (float*)p; p += (size_t)2 * 256 * 2048 * sizeof(float);
    float* Y      = (float*)p; p += (size_t)2 * 256 * 1024 * sizeof(float);
    float* zbuf   = (float*)p; p += (size_t)2 * 16 * 1024 * sizeof(float);
    float* imp    = (float*)p; p += (size_t)Bb * Ss * sizeof(float);
    float* hbuf   = (float*)p; p += (size_t)Bb * 64 * 512 * sizeof(float);
    float* qkvsel = (float*)p; p += (size_t)3 * 32 * 1024 * sizeof(float);
    float* beta   = (float*)p; p += (size_t)2 * 256 * sizeof(float);
    int* sel_idx  = (int*)p; p += (size_t)Bb * Kk * sizeof(int);
    int* cand_idx = (int*)p; p += (size_t)Bb * 64 * sizeof(int);
    int* ccount   = (int*)p; p += Bb * sizeof(int);

    // 1) prep: inits (1024) + transpose&pack x once (4096) + Ws1 T (512).
    prep_kernel<<<dim3(5632), 256, 0, stream>>>(
        x, xb, xbT, imp, hbuf, qkvsel, ccount, Ws1, W1Th, bv, Y, zbuf);
    // 2) approximate indexer GEMM -> imp (256 blocks, fence-free).
    gemm_ind<<<dim3(4, 64), 256, 0, stream>>>(xb, W1Th, bs1, Ws2, imp);
    // 3) fast candidate generation (single-wave argmax).
    topk_fast<<<dim3(Bb), 256, 0, stream>>>(imp, cand_idx, ccount);
    // 4) exact rescore: parallel partial-h, then fused finalize+selection.
    rescore_h<<<dim3(64, 16, Bb), 256, 0, stream>>>(x, Ws1, cand_idx, ccount, hbuf);
    rescore_fin_sel<<<dim3(Bb), 256, 0, stream>>>(
        hbuf, bs1, Ws2, cand_idx, ccount, sel_idx);
    // 5) exact f32 projections of the 32 selected rows.
    proj_sel<<<dim3(8, 3, 8), 256, 0, stream>>>(x, Wq, Wk, Wv, sel_idx, qkvsel);
    // 6) build algebraic operands C, D (-> ET), Vo^T, beta.
    build_cdvo<<<dim3(8, 16, 2), 256, 0, stream>>>(
        Wq, Wk, Wo, bq, bk, bv, qkvsel, beta, ET, VoT);
    // 7) score GEMM with fused sparse softmax (Wsp direct) + SdT.
    gemm_scores<<<dim3(4, 32, 2), 256, 0, stream>>>(xb, ET, beta, Wsp, SdT);
    // 8) dense column softmax only.
    sm_dense<<<dim3(256, 2), 256, 0, stream>>>(SdT, WdT);
    // 9) FUSED output GEMMs: sparse out (sel rows bias-only) + Y = W_dn @ X.
    gemm_bt2x<<<dim3(640), 256, 0, stream>>>(
        Wsp, VoT, bo, out, WdT, xbT, Y, sel_idx);
    // 10) dense tail: zbuf(+=bv) = Y@Wv; out[sel](+=bo) += z@Wo directly.
    dense_z2<<<dim3(16, 8, 2), 256, 0, stream>>>(Y, Wv, zbuf);
    dense_out2<<<dim3(16, 8, 2), 256, 0, stream>>>(zbuf, Wo, sel_idx, out);
}

// Round 10
// 237.981 us; speedup vs baseline: 1.1005x; 1.1005x over previous
//
#include <hip/hip_runtime.h>
#include <math.h>

// Problem constants
constexpr int Bb = 2, Ss = 2048, Dd = 1024, Hh = 16, Kk = 16;
constexpr float DELTA = 0.02f;   // candidate margin (~30 sigma of bf16 approx error)

typedef __bf16 bf16x8 __attribute__((ext_vector_type(8)));
typedef __bf16 bf16x4 __attribute__((ext_vector_type(4)));
typedef float  f32x4  __attribute__((ext_vector_type(4)));

__device__ __forceinline__ void gld_lds16(const void* g, void* l) {
    __builtin_amdgcn_global_load_lds(
        (const __attribute__((address_space(1))) unsigned int*)g,
        (__attribute__((address_space(3))) unsigned int*)l, 16, 0, 0);
}

// ---------------------------------------------------------------------------
// FUSED GEMM dispatch (R0-verified): uniform bf16 MFMA GEMM, 256x128 tile,
// BK=64, 512 threads / 8 waves. cb 0..23 QKV (bias + bf16 store); cb 24..27
// approximate indexer (relu*Ws2 row-reduce -> atomicAdd imp). Grid 448.
// ---------------------------------------------------------------------------
__global__ void __launch_bounds__(512) gemm_qkv_ind(
    const __bf16* __restrict__ xb, const __bf16* __restrict__ WqkvT,
    const __bf16* __restrict__ W1Th,
    const float* __restrict__ bq, const float* __restrict__ bk,
    const float* __restrict__ bv,
    __bf16* __restrict__ qb, __bf16* __restrict__ kb, __bf16* __restrict__ vb,
    const float* __restrict__ bs1, const float* __restrict__ Ws2,
    float* __restrict__ imp)
{
    __shared__ __bf16 As[256 * 64];   // 32 KB
    __shared__ __bf16 Bs[128 * 64];   // 16 KB

    const int bid  = blockIdx.x;
    const int cb   = bid % 28;
    const int bm   = (bid / 28) * 256;
    const int t    = threadIdx.x;
    const int wave = t >> 6;
    const int lane = t & 63;
    const int fr   = lane & 15;
    const int fq   = lane >> 4;
    const int K    = Dd;
    const bool ind = (cb >= 24);

    const __bf16* BT = ind ? (W1Th + (size_t)(cb - 24) * 128 * 1024)
                           : (WqkvT + (size_t)cb * 128 * 1024);

    const int wm = (wave & 3) * 64;
    const int wn = (wave >> 2) * 64;

    f32x4 acc[4][4] = {};

    for (int k0 = 0; k0 < K; k0 += 64) {
        #pragma unroll
        for (int l = 0; l < 4; ++l) {
            int c = l * 512 + t;
            int row = c >> 3, seg = (c & 7) ^ (row & 7);
            gld_lds16(xb + (size_t)(bm + row) * K + k0 + seg * 8,
                      As + (size_t)(l * 512 + wave * 64) * 8);
        }
        #pragma unroll
        for (int l = 0; l < 2; ++l) {
            int c = l * 512 + t;
            int row = c >> 3, seg = (c & 7) ^ (row & 7);
            gld_lds16(BT + (size_t)row * K + k0 + seg * 8,
                      Bs + (size_t)(l * 512 + wave * 64) * 8);
        }
        __syncthreads();

        #pragma unroll
        for (int s = 0; s < 2; ++s) {
            bf16x8 af[4], bf[4];
            #pragma unroll
            for (int i = 0; i < 4; ++i) {
                int row = wm + i * 16 + fr;
                af[i] = *(const bf16x8*)(As + row * 64 + (((s * 4 + fq) ^ (row & 7)) * 8));
            }
            #pragma unroll
            for (int j = 0; j < 4; ++j) {
                int row = wn + j * 16 + fr;
                bf[j] = *(const bf16x8*)(Bs + row * 64 + (((s * 4 + fq) ^ (row & 7)) * 8));
            }
            #pragma unroll
            for (int i = 0; i < 4; ++i)
                #pragma unroll
                for (int j = 0; j < 4; ++j)
                    acc[i][j] = __builtin_amdgcn_mfma_f32_16x16x32_bf16(af[i], bf[j], acc[i][j], 0, 0, 0);
        }
        __syncthreads();
    }

    const int cr = (lane >> 4) * 4;
    const int cc = lane & 15;

    if (!ind) {
        const int zone = cb >> 3;                       // 0=q 1=k 2=v
        const int cl0  = cb * 128 - zone * 1024;
        const float* bias = (zone == 0) ? bq : (zone == 1) ? bk : bv;
        __bf16*      C    = (zone == 0) ? qb : (zone == 1) ? kb : vb;
        #pragma unroll
        for (int j = 0; j < 4; ++j) {
            int col = cl0 + wn + j * 16 + cc;
            float bb = bias[col];
            #pragma unroll
            for (int i = 0; i < 4; ++i) {
                #pragma unroll
                for (int r = 0; r < 4; ++r)
                    C[(size_t)(bm + wm + i * 16 + cr + r) * Dd + col] =
                        (__bf16)(acc[i][j][r] + bb);
            }
        }
    } else {
        const int hc0 = (cb - 24) * 128;
        float bb[4], w2[4];
        #pragma unroll
        for (int j = 0; j < 4; ++j) {
            int col = hc0 + wn + j * 16 + cc;
            bb[j] = bs1[col];
            w2[j] = Ws2[col];
        }
        #pragma unroll
        for (int i = 0; i < 4; ++i) {
            #pragma unroll
            for (int r = 0; r < 4; ++r) {
                float vsum = 0.f;
                #pragma unroll
                for (int j = 0; j < 4; ++j)
                    vsum += fmaxf(acc[i][j][r] + bb[j], 0.f) * w2[j];
                #pragma unroll
                for (int off = 8; off > 0; off >>= 1)
                    vsum += __shfl_xor(vsum, off, 16);
                if (cc == 0)
                    atomicAdd(imp + (bm + wm + i * 16 + cr + r), vsum);
            }
        }
    }
}

// ---------------------------------------------------------------------------
// Out-projection GEMM (R0-verified): out = att @ WoT^T + bo, f32 out.
// 64x128 tile, BK=64. Grid (8, 64).
// ---------------------------------------------------------------------------
__global__ void __launch_bounds__(256) gemm_out(
    const __bf16* __restrict__ A, const __bf16* __restrict__ BT,
    const float* __restrict__ bias, float* __restrict__ C, int M, int N, int K)
{
    __shared__ __bf16 As[64 * 64];
    __shared__ __bf16 Bs[128 * 64];

    const int t    = threadIdx.x;
    const int wave = t >> 6;
    const int lane = t & 63;
    const int bm   = blockIdx.y * 64;
    const int bn   = blockIdx.x * 128;
    const int wm   = (wave & 1) * 32;
    const int wn   = (wave >> 1) * 64;
    const int fr   = lane & 15;
    const int fq   = lane >> 4;

    f32x4 acc[2][4] = {};

    for (int k0 = 0; k0 < K; k0 += 64) {
        #pragma unroll
        for (int l = 0; l < 2; ++l) {
            int c = l * 256 + t;
            int row = c >> 3, seg = (c & 7) ^ (row & 7);
            gld_lds16(A + (size_t)(bm + row) * K + k0 + seg * 8,
                      As + (size_t)(l * 256 + wave * 64) * 8);
        }
        #pragma unroll
        for (int l = 0; l < 4; ++l) {
            int c = l * 256 + t;
            int row = c >> 3, seg = (c & 7) ^ (row & 7);
            gld_lds16(BT + (size_t)(bn + row) * K + k0 + seg * 8,
                      Bs + (size_t)(l * 256 + wave * 64) * 8);
        }
        __syncthreads();

        #pragma unroll
        for (int s = 0; s < 2; ++s) {
            bf16x8 af[2], bf[4];
            #pragma unroll
            for (int i = 0; i < 2; ++i) {
                int row = wm + i * 16 + fr;
                af[i] = *(const bf16x8*)(As + row * 64 + (((s * 4 + fq) ^ (row & 7)) * 8));
            }
            #pragma unroll
            for (int j = 0; j < 4; ++j) {
                int row = wn + j * 16 + fr;
                bf[j] = *(const bf16x8*)(Bs + row * 64 + (((s * 4 + fq) ^ (row & 7)) * 8));
            }
            #pragma unroll
            for (int i = 0; i < 2; ++i)
                #pragma unroll
                for (int j = 0; j < 4; ++j)
                    acc[i][j] = __builtin_amdgcn_mfma_f32_16x16x32_bf16(af[i], bf[j], acc[i][j], 0, 0, 0);
        }
        __syncthreads();
    }

    const int cr = (lane >> 4) * 4;
    const int cc = lane & 15;
    #pragma unroll
    for (int j = 0; j < 4; ++j) {
        int col = bn + wn + j * 16 + cc;
        float bb = bias[col];
        #pragma unroll
        for (int i = 0; i < 2; ++i) {
            #pragma unroll
            for (int r = 0; r < 4; ++r)
                C[(size_t)(bm + wm + i * 16 + cr + r) * N + col] = acc[i][j][r] + bb;
        }
    }
}

// ---------------------------------------------------------------------------
// Merged prep (R0-verified): bid<4096 -> pack x (f32 -> bf16) + zero-init
// accumulators; bid>=4096 -> weight transpose+pack.
// ---------------------------------------------------------------------------
__global__ void __launch_bounds__(256) prep_kernel(
    const float* __restrict__ x, __bf16* __restrict__ xb,
    float* __restrict__ imp, float* __restrict__ oacc,
    float* __restrict__ lsum, float* __restrict__ hbuf,
    int* __restrict__ ccount,
    const float* __restrict__ W0, const float* __restrict__ W1,
    const float* __restrict__ W2, const float* __restrict__ W3,
    __bf16* __restrict__ WqkvT, __bf16* __restrict__ WoT,
    const float* __restrict__ Ws1, __bf16* __restrict__ Th)
{
    __shared__ float tile[32][33];
    const int bid = blockIdx.x;

    if (bid < 4096) {
        int i = bid * 256 + threadIdx.x;
        if (i < Bb * Ss) imp[i] = 0.f;
        if (i < Bb * Hh * Kk * 64) oacc[i] = 0.f;
        if (i < Bb * Hh * Kk) lsum[i] = 0.f;
        if (i < Bb * 64 * 512) hbuf[i] = 0.f;
        if (i < Bb) ccount[i] = 0;
        float4 v = ((const float4*)x)[i];
        bf16x4 h = { (__bf16)v.x, (__bf16)v.y, (__bf16)v.z, (__bf16)v.w };
        ((bf16x4*)xb)[i] = h;
        return;
    }

    int tid = bid - 4096;
    int z   = tid >> 10;
    int rem = tid & 1023;
    int n0  = (rem & 31) * 32;
    int k0  = (rem >> 5) * 32;
    int tx = threadIdx.x & 31, ty = threadIdx.x >> 5;

    if (z < 4) {
        const float* W = (z == 0) ? W0 : (z == 1) ? W1 : (z == 2) ? W2 : W3;
        __bf16*      T = (z < 3) ? (WqkvT + (size_t)z * 1024 * 1024) : WoT;
        #pragma unroll
        for (int i = 0; i < 32; i += 8)
            tile[ty + i][tx] = W[(size_t)(k0 + ty + i) * 1024 + n0 + tx];
        __syncthreads();
        #pragma unroll
        for (int i = 0; i < 32; i += 8)
            T[(size_t)(n0 + ty + i) * 1024 + k0 + tx] = (__bf16)tile[tx][ty + i];
    } else {
        if (n0 >= 512) return;
        #pragma unroll
        for (int i = 0; i < 32; i += 8)
            tile[ty + i][tx] = Ws1[(size_t)(k0 + ty + i) * 512 + n0 + tx];
        __syncthreads();
        #pragma unroll
        for (int i = 0; i < 32; i += 8)
            Th[(size_t)(n0 + ty + i) * 1024 + k0 + tx] = (__bf16)tile[tx][ty + i];
    }
}

// ---------------------------------------------------------------------------
// FAST candidate generation (proven R8, -12 us vs R0's topk_cand): wave-0
// argmax over LDS with no syncthreads in the 16-iter loop; threshold band
// with 256 threads. Grid (Bb), 256 threads.
// ---------------------------------------------------------------------------
__global__ void __launch_bounds__(256) topk_fast(
    const float* __restrict__ imp, int* __restrict__ cand_idx,
    int* __restrict__ ccount)
{
    __shared__ float vals[2048];
    __shared__ float thr_s;
    __shared__ int   cnt_s;
    const int b = blockIdx.x;
    const int t = threadIdx.x;

    #pragma unroll
    for (int e = 0; e < 8; ++e)
        vals[t + 256 * e] = imp[b * Ss + t + 256 * e];
    __syncthreads();

    if (t < 64) {
        const int base = t * 32;
        for (int it = 0; it < Kk; ++it) {
            float best = -1e30f; int bidx = 0x7fffffff;
            #pragma unroll 8
            for (int j = 0; j < 32; ++j) {
                float v = vals[base + j];
                if (v > best) { best = v; bidx = base + j; }
            }
            #pragma unroll
            for (int off = 32; off > 0; off >>= 1) {
                float ov = __shfl_xor(best, off, 64);
                int   oi = __shfl_xor(bidx, off, 64);
                if (ov > best || (ov == best && oi < bidx)) { best = ov; bidx = oi; }
            }
            if (t == 0) {
                cand_idx[b * 64 + it] = bidx;
                vals[bidx] = -1e30f;
                if (it == Kk - 1) { thr_s = best - DELTA; cnt_s = Kk; }
            }
        }
    }
    __syncthreads();

    float thr = thr_s;
    #pragma unroll
    for (int e = 0; e < 8; ++e) {
        if (vals[t + 256 * e] > thr) {
            int p = atomicAdd(&cnt_s, 1);
            if (p < 64) cand_idx[b * 64 + p] = t + 256 * e;
        }
    }
    __syncthreads();
    if (t == 0) ccount[b] = min(cnt_s, 64);
}

// ---------------------------------------------------------------------------
// Exact f32 rescore, phase 1 (R0-verified). Grid (64, 16, Bb).
// ---------------------------------------------------------------------------
__global__ void __launch_bounds__(256) rescore_h(
    const float* __restrict__ x, const float* __restrict__ Ws1,
    const int* __restrict__ cand_idx, const int* __restrict__ ccount,
    float* __restrict__ hbuf)
{
    const int c = blockIdx.x, kc = blockIdx.y, b = blockIdx.z;
    if (c >= ccount[b]) return;
    const int row = cand_idx[b * 64 + c];
    const int t = threadIdx.x;
    const int k0 = kc * 64;

    __shared__ float xs[64];
    if (t < 16)
        ((float4*)xs)[t] = ((const float4*)(x + ((size_t)(b * Ss + row)) * Dd + k0))[t];
    __syncthreads();

    float a0 = 0.f, a1 = 0.f;
    const float* W = Ws1 + (size_t)k0 * 512;
    #pragma unroll 16
    for (int kk = 0; kk < 64; ++kk) {
        float xv = xs[kk];
        a0 = fmaf(xv, W[kk * 512 + t], a0);
        a1 = fmaf(xv, W[kk * 512 + t + 256], a1);
    }
    float* hb = hbuf + ((size_t)(b * 64 + c)) * 512;
    atomicAdd(hb + t, a0);
    atomicAdd(hb + t + 256, a1);
}

// ---------------------------------------------------------------------------
// MERGED rescore phase-2 + final selection (proven R6/R8): z per candidate
// (4 threads each) then exact top-16 on wave 0. Grid (Bb), 256 threads.
// ---------------------------------------------------------------------------
__global__ void __launch_bounds__(256) rescore_fin_sel(
    const float* __restrict__ hbuf, const float* __restrict__ bs1,
    const float* __restrict__ Ws2, const int* __restrict__ cand_idx,
    const int* __restrict__ ccount, int* __restrict__ sel_idx)
{
    const int b = blockIdx.x;
    const int t = threadIdx.x;
    __shared__ float czv[64];
    __shared__ int   cidx[64];
    const int cntb = ccount[b];

    {
        const int cc = t >> 2, part = t & 3;
        const float* hb = hbuf + ((size_t)(b * 64 + cc)) * 512;
        float z = 0.f;
        const int j0 = part * 128;
        for (int j = j0; j < j0 + 128; ++j)
            z += fmaxf(hb[j] + bs1[j], 0.f) * Ws2[j];
        z += __shfl_xor(z, 1, 4);
        z += __shfl_xor(z, 2, 4);
        if (part == 0) { czv[cc] = z; cidx[cc] = cand_idx[b * 64 + cc]; }
    }
    __syncthreads();

    if (t < 64) {
        float val = (t < cntb) ? czv[t] : -1e30f;
        int   row = (t < cntb) ? cidx[t] : 0x7fffffff;
        for (int it = 0; it < Kk; ++it) {
            float bv = val; int br = row;
            #pragma unroll
            for (int off = 1; off < 64; off <<= 1) {
                float ov = __shfl_xor(bv, off, 64);
                int   orw = __shfl_xor(br, off, 64);
                if (ov > bv || (ov == bv && orw < br)) { bv = ov; br = orw; }
            }
            if (row == br) val = -1e30f;
            if (t == 0) sel_idx[b * Kk + it] = br;
        }
    }
}

// ---------------------------------------------------------------------------
// FUSED attention dispatch (R0-verified): blockIdx.x < 128 -> sparse path;
// else -> dense path (16 selected queries x 64-key chunk). Grid (160,Hh,Bb).
// ---------------------------------------------------------------------------
__global__ void __launch_bounds__(256) attn_all(
    const __bf16* __restrict__ q, const __bf16* __restrict__ k,
    const __bf16* __restrict__ v, const int* __restrict__ sel_idx,
    __bf16* __restrict__ att, float* __restrict__ lsum,
    float* __restrict__ oacc)
{
    __shared__ __align__(16) float sm[6720];   // 26.9 KB union
    const int b = blockIdx.z, h = blockIdx.y;
    const int t = threadIdx.x;

    if (blockIdx.x < 128) {
        // ---------------- sparse path ----------------
        float (*KT)[17]  = (float(*)[17])sm;            // 64x17
        float (*Vs)[64]  = (float(*)[64])(sm + 1088);   // 16x64
        float (*qsh)[65] = (float(*)[65])(sm + 2112);   // 16x65
        float (*wsh)[16] = (float(*)[16])(sm + 3152);   // 16x16
        int*  sj         = (int*)(sm + 3408);
        const int q0 = blockIdx.x * 16;

        if (t < 16) sj[t] = sel_idx[b * Kk + t];
        __syncthreads();

        {
            int row = t >> 4, d0 = (t & 15) * 4;
            bf16x4 kv = *(const bf16x4*)(k + ((size_t)(b * Ss + sj[row])) * Dd + h * 64 + d0);
            bf16x4 vv = *(const bf16x4*)(v + ((size_t)(b * Ss + sj[row])) * Dd + h * 64 + d0);
            bf16x4 qv = *(const bf16x4*)(q + ((size_t)(b * Ss + q0 + row)) * Dd + h * 64 + d0);
            #pragma unroll
            for (int i = 0; i < 4; ++i) {
                KT[d0 + i][row]  = (float)kv[i];
                Vs[row][d0 + i]  = (float)vv[i];
                qsh[row][d0 + i] = (float)qv[i];
            }
        }
        __syncthreads();

        const int wave = t >> 6, lane = t & 63;
        const int ql = lane >> 4, j = lane & 15;
        const int qi = wave * 4 + ql;

        float s = 0.f;
        #pragma unroll
        for (int d = 0; d < 64; ++d) s = fmaf(qsh[qi][d], KT[d][j], s);
        s *= 0.125f;

        float m = s;
        #pragma unroll
        for (int off = 8; off > 0; off >>= 1) m = fmaxf(m, __shfl_xor(m, off, 16));
        float e = __expf(s - m);
        float sum = e;
        #pragma unroll
        for (int off = 8; off > 0; off >>= 1) sum += __shfl_xor(sum, off, 16);
        wsh[qi][j] = e / sum;   // read back only within this wave

        #pragma unroll
        for (int q2 = 0; q2 < 4; ++q2) {
            int qq = wave * 4 + q2;
            float o = 0.f;
            #pragma unroll
            for (int jj = 0; jj < 16; ++jj)
                o = fmaf(wsh[qq][jj], Vs[jj][lane], o);
            att[((size_t)(b * Ss + q0 + qq)) * Dd + h * 64 + lane] = (__bf16)o;
        }
    } else {
        // ---------------- dense path (64-key chunk) ----------------
        float (*Ks)[68] = (float(*)[68])sm;             // 64x68 (reused for V)
        float (*Qs)[68] = (float(*)[68])(sm + 4352);    // 16x68
        float (*Es)[80] = (float(*)[80])(sm + 5440);    // 16x80
        const int j0 = (blockIdx.x - 128) * 64;

        #pragma unroll
        for (int l = 0; l < 2; ++l) {
            int c = t + 256 * l;
            int row = c >> 3, seg = c & 7;
            bf16x8 kv = *(const bf16x8*)(k + ((size_t)(b * Ss + j0 + row)) * Dd + h * 64 + seg * 8);
            #pragma unroll
            for (int e = 0; e < 8; ++e) Ks[row][seg * 8 + e] = (float)kv[e];
        }
        if (t < 128) {
            int row = t >> 3, seg = t & 7;
            int i = sel_idx[b * Kk + row];
            bf16x8 qv = *(const bf16x8*)(q + ((size_t)(b * Ss + i)) * Dd + h * 64 + seg * 8);
            #pragma unroll
            for (int e = 0; e < 8; ++e) Qs[row][seg * 8 + e] = (float)qv[e];
        }
        __syncthreads();

        const int qi = t >> 4, ks = t & 15;
        const int bhq = (b * Hh + h) * Kk + qi;
        float psum = 0.f;
        #pragma unroll
        for (int s8 = 0; s8 < 4; ++s8) {
            int j = ks + s8 * 16;
            float sdot = 0.f;
            #pragma unroll
            for (int d4 = 0; d4 < 16; ++d4) {
                float4 qv = *(const float4*)&Qs[qi][d4 * 4];
                float4 kv = *(const float4*)&Ks[j][d4 * 4];
                sdot += qv.x * kv.x + qv.y * kv.y + qv.z * kv.z + qv.w * kv.w;
            }
            float e = __expf(sdot * 0.125f);   // no max-sub: |s|<=~3, shift-inv
            Es[qi][j] = e;
            psum += e;
        }
        #pragma unroll
        for (int off = 8; off > 0; off >>= 1) psum += __shfl_xor(psum, off, 16);
        if (ks == 0) atomicAdd(lsum + bhq, psum);
        __syncthreads();   // Es complete; Ks reads done -> overwrite with V

        #pragma unroll
        for (int l = 0; l < 2; ++l) {
            int c = t + 256 * l;
            int row = c >> 3, seg = c & 7;
            bf16x8 vv = *(const bf16x8*)(v + ((size_t)(b * Ss + j0 + row)) * Dd + h * 64 + seg * 8);
            #pragma unroll
            for (int e = 0; e < 8; ++e) Ks[row][seg * 8 + e] = (float)vv[e];
        }
        __syncthreads();

        const int d = t & 63, qg = t >> 6;
        #pragma unroll
        for (int qq = 0; qq < 4; ++qq) {
            int qx = qg * 4 + qq;
            float o = 0.f;
            #pragma unroll 8
            for (int jj = 0; jj < 64; ++jj)
                o = fmaf(Es[qx][jj], Ks[jj][d], o);
            atomicAdd(oacc + (size_t)((b * Hh + h) * Kk + qx) * 64 + d, o);
        }
    }
}

// ---------------------------------------------------------------------------
// Dense attention finalize (R0-verified): att[selected rows] = oacc / lsum.
// ---------------------------------------------------------------------------
__global__ void __launch_bounds__(64) attn_dense_fin(
    const float* __restrict__ oacc, const float* __restrict__ lsum,
    const int* __restrict__ sel_idx, __bf16* __restrict__ att)
{
    int bid = blockIdx.x;
    int qi = bid & 15, h = (bid >> 4) & 15, b = bid >> 8;
    int bhq = (b * Hh + h) * Kk + qi;
    int i = sel_idx[b * Kk + qi];
    float val = oacc[(size_t)bhq * 64 + threadIdx.x] / lsum[bhq];
    att[((size_t)(b * Ss + i)) * Dd + h * 64 + threadIdx.x] = (__bf16)val;
}

// ---------------------------------------------------------------------------
extern "C" void kernel_launch(void* const* d_in, const int* in_sizes, int n_in,
                              void* d_out, int out_size, void* d_ws, size_t ws_size,
                              hipStream_t stream)
{
    const float* x   = (const float*)d_in[0];
    const float* Wq  = (const float*)d_in[1];
    const float* bq  = (const float*)d_in[2];
    const float* Wk  = (const float*)d_in[3];
    const float* bk  = (const float*)d_in[4];
    const float* Wv  = (const float*)d_in[5];
    const float* bv  = (const float*)d_in[6];
    const float* Wo  = (const float*)d_in[7];
    const float* bo  = (const float*)d_in[8];
    const float* Ws1 = (const float*)d_in[9];
    const float* bs1 = (const float*)d_in[10];
    const float* Ws2 = (const float*)d_in[11];
    float* out = (float*)d_out;

    const size_t MSD = (size_t)Bb * Ss * Dd;   // 4,194,304
    const int M = Bb * Ss;                     // 4096

    char* p = (char*)d_ws;
    __bf16* qb  = (__bf16*)p; p += MSD * sizeof(__bf16);
    __bf16* kb  = (__bf16*)p; p += MSD * sizeof(__bf16);
    __bf16* vb  = (__bf16*)p; p += MSD * sizeof(__bf16);
    __bf16* att = (__bf16*)p; p += MSD * sizeof(__bf16);
    __bf16* xb  = (__bf16*)p; p += MSD * sizeof(__bf16);
    __bf16* WqkvT = (__bf16*)p; p += (size_t)3 * Dd * Dd * sizeof(__bf16);
    __bf16* WoT   = (__bf16*)p; p += (size_t)Dd * Dd * sizeof(__bf16);
    __bf16* W1Th  = (__bf16*)p; p += (size_t)512 * Dd * sizeof(__bf16);
    float* imp  = (float*)p; p += (size_t)Bb * Ss * sizeof(float);
    int* sel_idx = (int*)p; p += (size_t)Bb * Kk * sizeof(int);
    float* oacc = (float*)p; p += (size_t)Bb * Hh * Kk * 64 * sizeof(float);
    float* lsum = (float*)p; p += (size_t)Bb * Hh * Kk * sizeof(float);
    float* hbuf = (float*)p; p += (size_t)Bb * 64 * 512 * sizeof(float);
    int* ccount   = (int*)p; p += Bb * sizeof(int);
    int* cand_idx = (int*)p; p += (size_t)Bb * 64 * sizeof(int);

    // 1) Merged prep: pack x -> bf16 (+ zero accumulators), weight transposes.
    prep_kernel<<<dim3(4096 + 5120), 256, 0, stream>>>(
        x, xb, imp, oacc, lsum, hbuf, ccount,
        Wq, Wk, Wv, Wo, WqkvT, WoT, Ws1, W1Th);
    // 2) FUSED: QKV projections + approximate indexer (256x128, BK=64).
    gemm_qkv_ind<<<dim3(448), 512, 0, stream>>>(
        xb, WqkvT, W1Th, bq, bk, bv, qb, kb, vb, bs1, Ws2, imp);
    // 3) Fast candidate generation (single-wave argmax, proven -12 us).
    topk_fast<<<dim3(Bb), 256, 0, stream>>>(imp, cand_idx, ccount);
    // 4) Exact f32 rescore: parallel partial-h, then fused finalize+select.
    rescore_h<<<dim3(64, 16, Bb), 256, 0, stream>>>(x, Ws1, cand_idx, ccount, hbuf);
    rescore_fin_sel<<<dim3(Bb), 256, 0, stream>>>(
        hbuf, bs1, Ws2, cand_idx, ccount, sel_idx);
    // 5) FUSED attention: sparse (x<128) + dense 64-key chunks (x>=128).
    attn_all<<<dim3(160, Hh, Bb), 256, 0, stream>>>(
        qb, kb, vb, sel_idx, att, lsum, oacc);
    attn_dense_fin<<<dim3(Bb * Hh * Kk), 64, 0, stream>>>(oacc, lsum, sel_idx, att);
    // 6) Output projection: 64x128 tile, BK=64, 512 blocks.
    gemm_out<<<dim3(8, 64), 256, 0, stream>>>(att, WoT, bo, out, M, Dd, Dd);
}